// Round 2
// baseline (177.900 us; speedup 1.0000x reference)
//
#include <hip/hip_runtime.h>
#include <cstdint>

typedef unsigned short u16;
typedef unsigned int   u32;
typedef __bf16 bf16x8 __attribute__((ext_vector_type(8)));
typedef float  f32x16 __attribute__((ext_vector_type(16)));
typedef u32    u32x4  __attribute__((ext_vector_type(4)));

#define OUT1 984064   // 16*248*248
#define OUT2 350464   // 16*16*37*37

// workspace layout (bytes)
// Ximg: [d:8][n:16][vblk:32][row:248][c:8] bf16  (col = d + 8*vblk + c)
#define XIMG_BYTES 16252928
#define XD_STRIDE  2031616            // 16*32*248*16 bytes per d-slice
// TmplP: [o:16][vblk:28][row:216][c:8] bf16     (col = 8*vblk + c)
#define TMPL_OFFB  16252928
#define TMPL_BYTES 1548288
#define PART_OFFB  17801216
#define PART_ELEMS (6*OUT2)           // [3 uq][2 gp] partial slabs
#define EFF_OFFB   26212352           // + 5184 B eff filters

// ---------------- k0: zero partial slabs + build effective 16x9x9 filters ----
__global__ void k0_init(const float* __restrict__ ft, const float* __restrict__ fnt,
                        float* __restrict__ partial, float* __restrict__ effw) {
  int t = blockIdx.x * 256 + threadIdx.x;
  for (int z = t; z < PART_ELEMS; z += gridDim.x * 256) partial[z] = 0.f;
  if (blockIdx.x == 0) {
    for (int idx = threadIdx.x; idx < 1296; idx += 256) {
      int c = idx / 81, s = idx - (idx / 81) * 81;
      effw[idx] = (c < 8) ? 0.5f * (ft[c*162 + s] + ft[c*162 + 81 + s])
                          : fnt[(c-8)*81 + s];
    }
  }
}

// ---------------- k1: f32 conv + relu + channel-normalize + bf16 packing -----
__global__ __launch_bounds__(256) void k1_conv(
    const float* __restrict__ x, const float* __restrict__ effw,
    float* __restrict__ out1, u16* __restrict__ Ximg, u16* __restrict__ TmplP) {
  __shared__ float xt[24][25];
  __shared__ float wsm[1296];
  const int tid = threadIdx.x;
  const int lx = tid & 15, ly = tid >> 4;
  const int bx = blockIdx.x, by = blockIdx.y;
  for (int idx = tid; idx < 1296; idx += 256) wsm[idx] = effw[idx];
  for (int idx = tid; idx < 576; idx += 256) {
    int ry = idx / 24, rx = idx - ry * 24;
    int gy = by*16 + ry; gy = gy > 255 ? 255 : gy;
    int gx = bx*16 + rx; gx = gx > 255 ? 255 : gx;
    xt[ry][rx] = x[gy*256 + gx];
  }
  __syncthreads();
  const int xg = bx*16 + lx, yg = by*16 + ly;
  if (yg >= 248) return;
  float s[16];
#pragma unroll
  for (int c = 0; c < 16; ++c) s[c] = 0.f;
  const bool valid = (xg < 248);
  if (valid) {
#pragma unroll
    for (int u = 0; u < 9; ++u)
#pragma unroll
      for (int v = 0; v < 9; ++v) {
        float xv = xt[ly + u][lx + v];
#pragma unroll
        for (int c = 0; c < 16; ++c)
          s[c] = __builtin_fmaf(xv, wsm[c*81 + u*9 + v], s[c]);
      }
    float sum = 2.2204460492503131e-16f;  // EPS, matches reference
#pragma unroll
    for (int c = 0; c < 16; ++c) { s[c] = s[c] > 0.f ? s[c] : 0.f; sum += s[c]; }
    float inv = 1.f / sum;
#pragma unroll
    for (int c = 0; c < 16; ++c) s[c] *= inv;
  }
#pragma unroll
  for (int c = 0; c < 16; ++c) {
    u16 hb = 0;
    if (valid) {
      out1[c*61504 + yg*248 + xg] = s[c];
      u32 ub = __builtin_bit_cast(u32, s[c]);
      hb = (u16)((ub + 0x7fffu + ((ub >> 16) & 1u)) >> 16);  // bf16 RNE
    }
    // 8 shifted copies, v-major tiled: every cell (incl. zero pads) written once
#pragma unroll
    for (int d = 0; d < 8; ++d) {
      int wp = xg - d;
      if (wp >= 0 && wp < 256)
        Ximg[(((d*16 + c)*32 + (wp >> 3))*248 + yg)*8 + (wp & 7)] = hb;
    }
    if (xg >= 18 && xg < 242 && yg >= 18 && yg < 234) {
      u16 tv = (xg < 230 && yg < 230) ? hb : (u16)0;
      int tc = xg - 18, tr = yg - 18;
      TmplP[((c*28 + (tc >> 3))*216 + tr)*8 + (tc & 7)] = tv;
    }
  }
}

// ---------------- k2: MFMA correlation ---------------------------------------
// Same math as round-0 (verified): WG=(j, 5-chain group g, u-quarter uq),
// MFMA 32x32x16 with (uu,p) slot trick. New: reg-staged prefetch pipeline,
// v-major tiled global layout (coalesced), XOR-swizzled LDS, XCD pinning.
#define F_LD(k,m,c) fl[(k)*1024 + (((m)&3) + 4*((m)>>3))*64 + ((c) + 32*(((m)>>2)&1))]

__global__ __launch_bounds__(256, 2) void k2_corr(
    const u16* __restrict__ Ximg, const u16* __restrict__ TmplP,
    float* __restrict__ partial) {
  extern __shared__ __align__(16) char lds[];   // img 40960 B + tmpl 36864 B
  const int bid = blockIdx.x;
  const int d   = bid & 7;            // shift residue == XCD (bid%8 pinning)
  const int m0  = bid >> 3;           // 0..59
  const int jq  = m0 % 5;
  const int cmb = m0 / 5;             // 0..11
  const int g   = cmb & 3;
  const int uq  = cmb >> 2;           // 0..2
  const int j   = d + 8*jq;
  if (j >= 37) return;                // 36 idle pad blocks
  const int U0  = 72*uq;
  const int R0  = 10*g + U0;
  const int tid  = threadIdx.x;
  const int lane = tid & 63;
  const int w    = tid >> 6;

  const char* xp = (const char*)Ximg + d*XD_STRIDE;
  const char* tp = (const char*)TmplP;

  // per-lane staging offsets (sv-invariant); global = coalesced row-runs
  int cimg[10], limg[10];
#pragma unroll
  for (int i = 0; i < 10; ++i) {
    int cid = w*640 + i*64 + lane;              // [n:16][h:2][row:80]
    int n = cid / 160, r1 = cid - n*160;
    int h = r1 / 80,  row0 = r1 - h*80;
    int grow = R0 + row0; if (grow > 247) grow = 247;   // clamped rows never read
    cimg[i] = ((n*32 + jq + h)*248 + grow) * 16;
    limg[i] = ((n*2 + h)*80 + (row0 ^ (n & 7))) * 16;   // XOR bank swizzle
  }
  int ctmp[9], ltmp[9];
#pragma unroll
  for (int i = 0; i < 9; ++i) {
    int cid = w*576 + i*64 + lane;              // [o:16][h:2][row:72]
    int o = cid / 144, r1 = cid - o*144;
    int h = r1 / 72,  row0 = r1 - h*72;
    ctmp[i] = ((o*28 + h)*216 + (U0 + row0)) * 16;
    ltmp[i] = 40960 + ((o*2 + h)*72 + (row0 ^ (o & 7))) * 16;
  }

  // fragment addressing constants
  const int fn16 = lane & 15;
  const int fuu  = (lane >> 4) & 1;
  const int fg   = lane >> 5;
  const int s7   = fn16 & 7;
  const int rbase = 18*w + fuu;
  const int aU = (fn16*2 + fg)*80;
  const int bU = (fn16*2 + fg)*72;

  f32x16 acc[5];
#pragma unroll
  for (int k = 0; k < 5; ++k)
#pragma unroll
    for (int q = 0; q < 16; ++q) acc[k][q] = 0.f;

  // prologue: prefetch sv=0 into registers
  u32x4 rA[10]; u32x4 rB[9];
#pragma unroll
  for (int i = 0; i < 10; ++i) rA[i] = *(const u32x4*)(xp + cimg[i]);
#pragma unroll
  for (int i = 0; i < 9; ++i)  rB[i] = *(const u32x4*)(tp + ctmp[i]);

  for (int sv = 0; sv < 14; ++sv) {
    __builtin_amdgcn_s_barrier();           // all waves done reading prev tile
#pragma unroll
    for (int i = 0; i < 10; ++i) *(u32x4*)(lds + limg[i]) = rA[i];
#pragma unroll
    for (int i = 0; i < 9; ++i)  *(u32x4*)(lds + ltmp[i]) = rB[i];
    if (sv < 13) {                          // issue next-tile loads: latency
      const int svb = (sv+1)*7936;          // hides under MFMA phase (T14)
      const int svt = (sv+1)*6912;
#pragma unroll
      for (int i = 0; i < 10; ++i) rA[i] = *(const u32x4*)(xp + cimg[i] + svb);
#pragma unroll
      for (int i = 0; i < 9; ++i)  rB[i] = *(const u32x4*)(tp + ctmp[i] + svt);
    }
    asm volatile("s_waitcnt lgkmcnt(0)" ::: "memory");  // ds_writes done; NO vmcnt drain
    __builtin_amdgcn_s_barrier();
    __builtin_amdgcn_sched_barrier(0);      // rule #18: don't hoist ds_reads above

    bf16x8 ar[5];                           // 5-deep A ring on diagonal r=i0+u0
#pragma unroll
    for (int m = 0; m < 5; ++m)
      ar[m] = *(const bf16x8*)(lds + ((aU + ((rbase + 2*m) ^ s7)) << 4));
#pragma unroll
    for (int t = 0; t < 9; ++t) {
      bf16x8 bf = *(const bf16x8*)(lds + 40960 + ((bU + ((rbase + 2*t) ^ s7)) << 4));
#pragma unroll
      for (int k = 0; k < 5; ++k)
        acc[k] = __builtin_amdgcn_mfma_f32_32x32x16_bf16(ar[(k+t)%5], bf, acc[k], 0, 0, 0);
      if (t < 8) ar[t%5] = *(const bf16x8*)(lds + ((aU + ((rbase + 2*(t+5)) ^ s7)) << 4));
    }
  }
  __syncthreads();

  // deterministic cross-wave fold in LDS (waves add sequentially)
  float* fl = (float*)lds;
  for (int z = tid; z < 5120; z += 256) fl[z] = 0.f;
  __syncthreads();
  for (int ww = 0; ww < 4; ++ww) {
    if (w == ww) {
#pragma unroll
      for (int k = 0; k < 5; ++k) {
        if (!(g == 3 && k == 4)) {          // g3 chain 4 duplicates i0=36: exclude
#pragma unroll
          for (int q = 0; q < 16; ++q)
            fl[k*1024 + q*64 + lane] += acc[k][q];
        }
      }
    }
    __syncthreads();
  }

  // emit 11 output rows [10g-1, 10g+9]; slabs [uq][g&1] are write-disjoint
  const int n = (tid >> 4) & 15;
  const int o = tid & 15;
  float* slab = partial + (uq*2 + (g & 1)) * OUT2;
  for (int ii = 0; ii < 11; ++ii) {
    const int i = 10*g - 1 + ii;
    if (i < 0 || i >= 37) continue;
    const int dd = ii - 1;
    float v;
    if (!(dd & 1)) {                        // diag: (uu,p)=(0,0)+(1,1)
      const int k = dd >> 1;
      v = F_LD(k, n, o) + F_LD(k, n+16, o+16);
    } else {
      v = 0.f;
      if (dd >= 1) v += F_LD((dd-1) >> 1, n+16, o);   // (1,0) from left chain
      const int kr = (dd+1) >> 1;
      if (kr <= 4) v += F_LD(kr, n, o+16);            // (0,1) from right chain
    }
    slab[(o*16 + n)*1369 + i*37 + j] = v;
  }
}

// ---------------- k3: reduce 6 partial slabs + scale -------------------------
__global__ void k3_reduce(const float* __restrict__ partial, float* __restrict__ out2) {
  const int idx = blockIdx.x*256 + threadIdx.x;
  float s = 0.f;
#pragma unroll
  for (int t = 0; t < 6; ++t) s += partial[t*OUT2 + idx];
  out2[idx] = s * (1.0f / 44944.0f);
}

extern "C" void kernel_launch(void* const* d_in, const int* in_sizes, int n_in,
                              void* d_out, int out_size, void* d_ws, size_t ws_size,
                              hipStream_t stream) {
  (void)in_sizes; (void)n_in; (void)out_size; (void)ws_size;
  const float* x   = (const float*)d_in[0];
  const float* ft  = (const float*)d_in[1];
  const float* fnt = (const float*)d_in[2];
  float* out = (float*)d_out;
  char*  ws  = (char*)d_ws;
  u16*   Ximg    = (u16*)ws;
  u16*   TmplP   = (u16*)(ws + TMPL_OFFB);
  float* partial = (float*)(ws + PART_OFFB);
  float* effw    = (float*)(ws + EFF_OFFB);

  hipFuncSetAttribute((const void*)k2_corr,
                      hipFuncAttributeMaxDynamicSharedMemorySize, 77824);

  k0_init<<<512, 256, 0, stream>>>(ft, fnt, partial, effw);
  k1_conv<<<dim3(17, 16), 256, 0, stream>>>(x, effw, out, Ximg, TmplP);
  k2_corr<<<480, 256, 77824, stream>>>(Ximg, TmplP, partial);
  k3_reduce<<<1369, 256, 0, stream>>>(partial, out + OUT1);
}

// Round 3
// 93.335 us; speedup vs baseline: 1.9060x; 1.9060x over previous
//
#include <hip/hip_runtime.h>
#include <cstdint>

typedef unsigned short u16;
typedef unsigned int   u32;
typedef __bf16 bf16x8 __attribute__((ext_vector_type(8)));
typedef float  f32x16 __attribute__((ext_vector_type(16)));
typedef u32    u32x4  __attribute__((ext_vector_type(4)));

#define OUT1 984064   // 16*248*248
#define OUT2 350464   // 16*16*37*37

// workspace layout (bytes)
// Ximg2: [d:8][vb:32][row:248][n:16][c:8] bf16   (col = d + 8*vb + c)
#define XIMG_OFFB  0
#define XD_STRIDE  2031616           // 32*248*16*8*2
// Tmpl2: [vb:28][row:216][o:16][c:8] bf16        (col = 8*vb + c, zero-padded)
#define TMPL_OFFB  16252928
#define PART_OFFB  17801216
#define PART_ELEMS (6*OUT2)          // [3 uq][2 gp] partial slabs
#define EFF_OFFB   26212352
#define XC_OFFB    26217536          // Xc: [c:16][row:248][col:264] bf16

// ---------------- k0: zero partial slabs + build effective 16x9x9 filters ----
__global__ void k0_init(const float* __restrict__ ft, const float* __restrict__ fnt,
                        float* __restrict__ partial, float* __restrict__ effw) {
  int t = blockIdx.x * 256 + threadIdx.x;
  for (int z = t; z < PART_ELEMS; z += gridDim.x * 256) partial[z] = 0.f;
  if (blockIdx.x == 0) {
    for (int idx = threadIdx.x; idx < 1296; idx += 256) {
      int c = idx / 81, s = idx - (idx / 81) * 81;
      effw[idx] = (c < 8) ? 0.5f * (ft[c*162 + s] + ft[c*162 + 81 + s])
                          : fnt[(c-8)*81 + s];
    }
  }
}

// ---------------- k1: f32 conv + relu + normalize -> out1 + canonical bf16 Xc
__global__ __launch_bounds__(256) void k1_conv(
    const float* __restrict__ x, const float* __restrict__ effw,
    float* __restrict__ out1, u16* __restrict__ Xc) {
  __shared__ float xt[24][25];
  __shared__ float wsm[1296];
  const int tid = threadIdx.x;
  const int lx = tid & 15, ly = tid >> 4;
  const int bx = blockIdx.x, by = blockIdx.y;
  for (int idx = tid; idx < 1296; idx += 256) wsm[idx] = effw[idx];
  for (int idx = tid; idx < 576; idx += 256) {
    int ry = idx / 24, rx = idx - ry * 24;
    int gy = by*16 + ry; gy = gy > 255 ? 255 : gy;
    int gx = bx*16 + rx; gx = gx > 255 ? 255 : gx;
    xt[ry][rx] = x[gy*256 + gx];
  }
  __syncthreads();
  const int xg = bx*16 + lx, yg = by*16 + ly;
  if (yg >= 248) return;
  float s[16];
#pragma unroll
  for (int c = 0; c < 16; ++c) s[c] = 0.f;
  const bool valid = (xg < 248);
  if (valid) {
#pragma unroll
    for (int u = 0; u < 9; ++u)
#pragma unroll
      for (int v = 0; v < 9; ++v) {
        float xv = xt[ly + u][lx + v];
#pragma unroll
        for (int c = 0; c < 16; ++c)
          s[c] = __builtin_fmaf(xv, wsm[c*81 + u*9 + v], s[c]);
      }
    float sum = 2.2204460492503131e-16f;  // EPS, matches reference
#pragma unroll
    for (int c = 0; c < 16; ++c) { s[c] = s[c] > 0.f ? s[c] : 0.f; sum += s[c]; }
    float inv = 1.f / sum;
#pragma unroll
    for (int c = 0; c < 16; ++c) s[c] *= inv;
  }
#pragma unroll
  for (int c = 0; c < 16; ++c) {
    u16 hb = 0;
    if (valid) {
      out1[c*61504 + yg*248 + xg] = s[c];
      u32 ub = __builtin_bit_cast(u32, s[c]);
      hb = (u16)((ub + 0x7fffu + ((ub >> 16) & 1u)) >> 16);  // bf16 RNE
    }
    if (xg < 264) Xc[(c*248 + yg)*264 + xg] = hb;  // cols 248..263 get zeros
  }
}

// ---------------- k1b: coalesced expansion Xc -> Ximg2 (8 shifts) + Tmpl2 ----
__global__ __launch_bounds__(256) void k1b_expand(
    const u16* __restrict__ Xc, u16* __restrict__ ws16) {
  const int cid = blockIdx.x*256 + threadIdx.x;
  const u32* src = (const u32*)Xc;
  if (cid < 1015808) {                       // Ximg2: 8*32*248*16 chunks of 16B
    int n  = cid & 15;
    int r1 = cid >> 4;
    int row = r1 % 248;
    int r2  = r1 / 248;
    int vb  = r2 & 31;
    int d   = r2 >> 5;
    int colb = (d & ~1) + 8*vb;              // even -> 4B-aligned dword index
    int so = (n*248 + row)*132 + (colb >> 1);
    u32 a0 = src[so], a1 = src[so+1], a2 = src[so+2], a3 = src[so+3], a4 = src[so+4];
    u32x4 v;
    if (d & 1) {                             // odd shift: 16-bit funnel
      v[0] = (a0 >> 16) | (a1 << 16); v[1] = (a1 >> 16) | (a2 << 16);
      v[2] = (a2 >> 16) | (a3 << 16); v[3] = (a3 >> 16) | (a4 << 16);
    } else { v[0] = a0; v[1] = a1; v[2] = a2; v[3] = a3; }
    *(u32x4*)(ws16 + (size_t)cid*8) = v;
  } else if (cid < 1015808 + 96768) {        // Tmpl2: 28*216*16 chunks of 16B
    int t  = cid - 1015808;
    int o  = t & 15;
    int r1 = t >> 4;
    int tr = r1 % 216;
    int vb = r1 / 216;
    u32x4 v = {0u, 0u, 0u, 0u};
    if (tr < 212 && vb < 27) {
      int so = (o*248 + tr + 18)*132 + ((18 + 8*vb) >> 1);
      v[0] = src[so]; v[1] = src[so+1]; v[2] = src[so+2]; v[3] = src[so+3];
      if (vb == 26) { v[2] = 0u; v[3] = 0u; }  // cols 212..215 are pad
    }
    *(u32x4*)(ws16 + (size_t)(TMPL_OFFB/2) + (size_t)t*8) = v;
  }
}

// ---------------- k2: MFMA correlation, LDS-free main loop -------------------
// Math identical to verified round-1: WG=(j, 5-chain group g, u-quarter uq),
// MFMA 32x32x16, slot trick (uu,p). Fragments load DIRECTLY from L2-resident
// fragment-major global tiles (no LDS reuse exists in this decomposition).
#define F_LD(k,m,c) fl[(k)*1024 + (((m)&3) + 4*((m)>>3))*64 + ((c) + 32*(((m)>>2)&1))]

__global__ __launch_bounds__(256, 2) void k2_corr(
    const u16* __restrict__ Ximg2, const u16* __restrict__ Tmpl2,
    float* __restrict__ partial) {
  __shared__ float fl[5120];
  const int bid = blockIdx.x;
  const int d   = bid & 7;            // shift residue (XCD pinning heuristic)
  const int m0  = bid >> 3;           // 0..59
  const int jq  = m0 % 5;
  const int cmb = m0 / 5;             // 0..11
  const int g   = cmb & 3;
  const int uq  = cmb >> 2;           // 0..2
  const int j   = d + 8*jq;
  if (j >= 37) return;                // 36 idle pad blocks
  const int U0  = 72*uq;
  const int R0  = 10*g + U0;
  const int tid  = threadIdx.x;
  const int lane = tid & 63;
  const int w    = tid >> 6;

  const int fn16 = lane & 15;
  const int fuu  = (lane >> 4) & 1;
  const int fg   = lane >> 5;

  const char* xp = (const char*)Ximg2 + d*XD_STRIDE + (jq + fg)*63488 + fn16*16;
  const char* tp = (const char*)Tmpl2 + fg*55296 + fn16*16;

  // sv-invariant per-lane row offsets (bytes)
  int aR[13], bR[9];
#pragma unroll
  for (int q = 0; q < 13; ++q) {
    int r = R0 + fuu + 18*w + 2*q;
    if (r > 247) r = 247;             // clamped rows only ever pair with zero B
    aR[q] = r*256;
  }
#pragma unroll
  for (int t = 0; t < 9; ++t)
    bR[t] = (U0 + fuu + 18*w + 2*t)*256;   // max 215 < 216, rows >=212 are zeros

  f32x16 acc[5];
#pragma unroll
  for (int k = 0; k < 5; ++k)
#pragma unroll
    for (int q = 0; q < 16; ++q) acc[k][q] = 0.f;

#pragma unroll 1
  for (int sv = 0; sv < 14; ++sv) {
    const char* xs = xp + sv*126976;  // advance 2 vblks
    const char* ts = tp + sv*110592;
    u32x4 af[13], bf[9];
#pragma unroll
    for (int q = 0; q < 13; ++q) af[q] = *(const u32x4*)(xs + aR[q]);
#pragma unroll
    for (int t = 0; t < 9; ++t)  bf[t] = *(const u32x4*)(ts + bR[t]);
#pragma unroll
    for (int t = 0; t < 9; ++t) {
      bf16x8 b = __builtin_bit_cast(bf16x8, bf[t]);
#pragma unroll
      for (int k = 0; k < 5; ++k)
        acc[k] = __builtin_amdgcn_mfma_f32_32x32x16_bf16(
                   __builtin_bit_cast(bf16x8, af[k + t]), b, acc[k], 0, 0, 0);
    }
  }
  __syncthreads();

  // deterministic cross-wave fold in LDS (waves add sequentially)
  for (int z = tid; z < 5120; z += 256) fl[z] = 0.f;
  __syncthreads();
  for (int ww = 0; ww < 4; ++ww) {
    if (w == ww) {
#pragma unroll
      for (int k = 0; k < 5; ++k) {
        if (!(g == 3 && k == 4)) {    // g3 chain 4 duplicates i0=36: exclude
#pragma unroll
          for (int q = 0; q < 16; ++q)
            fl[k*1024 + q*64 + lane] += acc[k][q];
        }
      }
    }
    __syncthreads();
  }

  // emit 11 output rows [10g-1, 10g+9]; slabs [uq][g&1] are write-disjoint
  const int n = (tid >> 4) & 15;
  const int o = tid & 15;
  float* slab = partial + (uq*2 + (g & 1)) * OUT2;
  for (int ii = 0; ii < 11; ++ii) {
    const int i = 10*g - 1 + ii;
    if (i < 0 || i >= 37) continue;
    const int dd = ii - 1;
    float v;
    if (!(dd & 1)) {                  // diag: (uu,p)=(0,0)+(1,1)
      const int k = dd >> 1;
      v = F_LD(k, n, o) + F_LD(k, n+16, o+16);
    } else {
      v = 0.f;
      if (dd >= 1) v += F_LD((dd-1) >> 1, n+16, o);   // (1,0) from left chain
      const int kr = (dd+1) >> 1;
      if (kr <= 4) v += F_LD(kr, n, o+16);            // (0,1) from right chain
    }
    slab[(o*16 + n)*1369 + i*37 + j] = v;
  }
}

// ---------------- k3: reduce 6 partial slabs + scale -------------------------
__global__ void k3_reduce(const float* __restrict__ partial, float* __restrict__ out2) {
  const int idx = blockIdx.x*256 + threadIdx.x;
  float s = 0.f;
#pragma unroll
  for (int t = 0; t < 6; ++t) s += partial[t*OUT2 + idx];
  out2[idx] = s * (1.0f / 44944.0f);
}

extern "C" void kernel_launch(void* const* d_in, const int* in_sizes, int n_in,
                              void* d_out, int out_size, void* d_ws, size_t ws_size,
                              hipStream_t stream) {
  (void)in_sizes; (void)n_in; (void)out_size; (void)ws_size;
  const float* x   = (const float*)d_in[0];
  const float* ft  = (const float*)d_in[1];
  const float* fnt = (const float*)d_in[2];
  float* out = (float*)d_out;
  char*  ws  = (char*)d_ws;
  u16*   Ximg2   = (u16*)ws;
  u16*   Tmpl2   = (u16*)(ws + TMPL_OFFB);
  float* partial = (float*)(ws + PART_OFFB);
  float* effw    = (float*)(ws + EFF_OFFB);
  u16*   Xc      = (u16*)(ws + XC_OFFB);

  k0_init<<<512, 256, 0, stream>>>(ft, fnt, partial, effw);
  k1_conv<<<dim3(17, 16), 256, 0, stream>>>(x, effw, out, Xc);
  k1b_expand<<<4346, 256, 0, stream>>>(Xc, (u16*)ws);
  k2_corr<<<480, 256, 0, stream>>>(Ximg2, Tmpl2, partial);
  k3_reduce<<<1369, 256, 0, stream>>>(partial, out + OUT1);
}

// Round 4
// 74.648 us; speedup vs baseline: 2.3832x; 1.2503x over previous
//
#include <hip/hip_runtime.h>
#include <cstdint>

typedef unsigned short u16;
typedef unsigned int   u32;
typedef unsigned long long u64;
typedef __bf16 bf16x8 __attribute__((ext_vector_type(8)));
typedef float  f32x16 __attribute__((ext_vector_type(16)));
typedef u32    u32x4  __attribute__((ext_vector_type(4)));

#define OUT1 984064   // 16*248*248
#define OUT2 350464   // 16*16*37*37

// workspace layout (bytes)
// Ximg2: [d:8][vb:32][row:248][n:16][c:8] bf16   (col = d + 8*vb + c)
#define XD_STRIDE  2031616           // 32 vb * 63488
// Tmpl2: [vb:28][row:216][o:16][c:8] bf16        (col = 8*vb + c, zero-padded)
#define TMPL_OFFB  16252928
#define PART_OFFB  17801216
#define PART_ELEMS (6*OUT2)          // [3 uq][2 gp] partial slabs
#define XC_OFFB    26212352          // Xc: [c:16][row:248][col:264] bf16

// ---------------- k1: f32 conv + relu + normalize -> out1 + canonical bf16 Xc
__global__ __launch_bounds__(256) void k1_conv(
    const float* __restrict__ x, const float* __restrict__ ft,
    const float* __restrict__ fnt, float* __restrict__ out1,
    u16* __restrict__ Xc) {
  __shared__ float xt[24][25];
  __shared__ float wsm[1296];
  const int tid = threadIdx.x;
  const int lx = tid & 15, ly = tid >> 4;
  const int bx = blockIdx.x, by = blockIdx.y;
  for (int idx = tid; idx < 1296; idx += 256) {   // effw built in-block (k0 gone)
    int c = idx / 81, s = idx - (idx / 81) * 81;
    wsm[idx] = (c < 8) ? 0.5f * (ft[c*162 + s] + ft[c*162 + 81 + s])
                       : fnt[(c-8)*81 + s];
  }
  for (int idx = tid; idx < 576; idx += 256) {
    int ry = idx / 24, rx = idx - ry * 24;
    int gy = by*16 + ry; gy = gy > 255 ? 255 : gy;
    int gx = bx*16 + rx; gx = gx > 255 ? 255 : gx;
    xt[ry][rx] = x[gy*256 + gx];
  }
  __syncthreads();
  const int xg = bx*16 + lx, yg = by*16 + ly;
  if (yg >= 248) return;
  float s[16];
#pragma unroll
  for (int c = 0; c < 16; ++c) s[c] = 0.f;
  const bool valid = (xg < 248);
  if (valid) {
#pragma unroll
    for (int u = 0; u < 9; ++u)
#pragma unroll
      for (int v = 0; v < 9; ++v) {
        float xv = xt[ly + u][lx + v];
#pragma unroll
        for (int c = 0; c < 16; ++c)
          s[c] = __builtin_fmaf(xv, wsm[c*81 + u*9 + v], s[c]);
      }
    float sum = 2.2204460492503131e-16f;  // EPS, matches reference
#pragma unroll
    for (int c = 0; c < 16; ++c) { s[c] = s[c] > 0.f ? s[c] : 0.f; sum += s[c]; }
    float inv = 1.f / sum;
#pragma unroll
    for (int c = 0; c < 16; ++c) s[c] *= inv;
  }
#pragma unroll
  for (int c = 0; c < 16; ++c) {
    u16 hb = 0;
    if (valid) {
      out1[c*61504 + yg*248 + xg] = s[c];
      u32 ub = __builtin_bit_cast(u32, s[c]);
      hb = (u16)((ub + 0x7fffu + ((ub >> 16) & 1u)) >> 16);  // bf16 RNE
    }
    if (xg < 264) Xc[(c*248 + yg)*264 + xg] = hb;  // cols 248..263 get zeros
  }
}

// ---------------- k1b: coalesced expansion Xc -> Ximg2 + Tmpl2; zero partial -
__global__ __launch_bounds__(256) void k1b_expand(
    const u16* __restrict__ Xc, u16* __restrict__ ws16, float* __restrict__ partial) {
  const int cid = blockIdx.x*256 + threadIdx.x;
  for (int z = cid; z < PART_ELEMS; z += 4346*256) partial[z] = 0.f;
  const u32* src = (const u32*)Xc;
  if (cid < 1015808) {                       // Ximg2: 8*32*248*16 chunks of 16B
    int n  = cid & 15;
    int r1 = cid >> 4;
    int row = r1 % 248;
    int r2  = r1 / 248;
    int vb  = r2 & 31;
    int d   = r2 >> 5;
    int colb = (d & ~1) + 8*vb;              // even -> 4B-aligned dword index
    int so = (n*248 + row)*132 + (colb >> 1);
    u32 a0 = src[so], a1 = src[so+1], a2 = src[so+2], a3 = src[so+3], a4 = src[so+4];
    u32x4 v;
    if (d & 1) {                             // odd shift: 16-bit funnel
      v[0] = (a0 >> 16) | (a1 << 16); v[1] = (a1 >> 16) | (a2 << 16);
      v[2] = (a2 >> 16) | (a3 << 16); v[3] = (a3 >> 16) | (a4 << 16);
    } else { v[0] = a0; v[1] = a1; v[2] = a2; v[3] = a3; }
    *(u32x4*)(ws16 + (size_t)cid*8) = v;
  } else if (cid < 1015808 + 96768) {        // Tmpl2: 28*216*16 chunks of 16B
    int t  = cid - 1015808;
    int o  = t & 15;
    int r1 = t >> 4;
    int tr = r1 % 216;
    int vb = r1 / 216;
    u32x4 v = {0u, 0u, 0u, 0u};
    if (tr < 212 && vb < 27) {
      int so = (o*248 + tr + 18)*132 + ((18 + 8*vb) >> 1);
      v[0] = src[so]; v[1] = src[so+1]; v[2] = src[so+2]; v[3] = src[so+3];
      if (vb == 26) { v[2] = 0u; v[3] = 0u; }  // cols 212..215 are pad
    }
    *(u32x4*)(ws16 + (size_t)(TMPL_OFFB/2) + (size_t)t*8) = v;
  }
}

// ---------------- k2: MFMA correlation, counted-vmcnt register pipeline ------
// Math identical to verified round-3. New: inline-asm buffer_load_dwordx4 with
// manual counted vmcnt (T4) + one-sv-ahead prefetch into parity buffers (T14).
// Issue order per sv: G0={a0..a4,b0}, Gt={a(4+t),b(t)} t=1..8  (22 loads).
// Steady-state waits: t=0 -> vmcnt(16); t>=1 -> vmcnt(20). Last sv: 16-2t.
#define F_LD(k,m,c) fl[(k)*1024 + (((m)&3) + 4*((m)>>3))*64 + ((c) + 32*(((m)>>2)&1))]

#define LOADA(DST,q,SO) asm volatile("buffer_load_dwordx4 %0, %1, %2, %3 offen" \
  : "=v"(DST[q]) : "v"(voffA[q]), "s"(srdA), "s"(SO));
#define LOADB(DST,t,SO) asm volatile("buffer_load_dwordx4 %0, %1, %2, %3 offen" \
  : "=v"(DST[t]) : "v"(voffB[t]), "s"(srdB), "s"(SO));
#define ISSUE_G0(NA,NB,SA,SB) LOADA(NA,0,SA) LOADA(NA,1,SA) LOADA(NA,2,SA) \
  LOADA(NA,3,SA) LOADA(NA,4,SA) LOADB(NB,0,SB)
#define ISSUE_GT(NA,NB,t,SA,SB) LOADA(NA,4+t,SA) LOADB(NB,t,SB)
// waits thread the newly-arrived regs ("+v") so MFMAs can't hoist above them
#define W6(N,CA,CB) asm volatile("s_waitcnt vmcnt(" #N ")" : "+v"(CA[0]), \
  "+v"(CA[1]),"+v"(CA[2]),"+v"(CA[3]),"+v"(CA[4]),"+v"(CB[0]) :: );
#define W2(N,CA,CB,t) asm volatile("s_waitcnt vmcnt(" #N ")" \
  : "+v"(CA[4+t]),"+v"(CB[t]) :: );
#define MF5(CA,CB,t) { bf16x8 _bb = __builtin_bit_cast(bf16x8, CB[t]); \
  acc[0]=__builtin_amdgcn_mfma_f32_32x32x16_bf16(__builtin_bit_cast(bf16x8,CA[t+0]),_bb,acc[0],0,0,0); \
  acc[1]=__builtin_amdgcn_mfma_f32_32x32x16_bf16(__builtin_bit_cast(bf16x8,CA[t+1]),_bb,acc[1],0,0,0); \
  acc[2]=__builtin_amdgcn_mfma_f32_32x32x16_bf16(__builtin_bit_cast(bf16x8,CA[t+2]),_bb,acc[2],0,0,0); \
  acc[3]=__builtin_amdgcn_mfma_f32_32x32x16_bf16(__builtin_bit_cast(bf16x8,CA[t+3]),_bb,acc[3],0,0,0); \
  acc[4]=__builtin_amdgcn_mfma_f32_32x32x16_bf16(__builtin_bit_cast(bf16x8,CA[t+4]),_bb,acc[4],0,0,0); }
#define HALF_PF(CA,CB,NA,NB,SA,SB) \
  W6(16,CA,CB)   MF5(CA,CB,0) ISSUE_G0(NA,NB,SA,SB) \
  W2(20,CA,CB,1) MF5(CA,CB,1) ISSUE_GT(NA,NB,1,SA,SB) \
  W2(20,CA,CB,2) MF5(CA,CB,2) ISSUE_GT(NA,NB,2,SA,SB) \
  W2(20,CA,CB,3) MF5(CA,CB,3) ISSUE_GT(NA,NB,3,SA,SB) \
  W2(20,CA,CB,4) MF5(CA,CB,4) ISSUE_GT(NA,NB,4,SA,SB) \
  W2(20,CA,CB,5) MF5(CA,CB,5) ISSUE_GT(NA,NB,5,SA,SB) \
  W2(20,CA,CB,6) MF5(CA,CB,6) ISSUE_GT(NA,NB,6,SA,SB) \
  W2(20,CA,CB,7) MF5(CA,CB,7) ISSUE_GT(NA,NB,7,SA,SB) \
  W2(20,CA,CB,8) MF5(CA,CB,8) ISSUE_GT(NA,NB,8,SA,SB)
#define HALF_LAST(CA,CB) \
  W6(16,CA,CB)   MF5(CA,CB,0) \
  W2(14,CA,CB,1) MF5(CA,CB,1) \
  W2(12,CA,CB,2) MF5(CA,CB,2) \
  W2(10,CA,CB,3) MF5(CA,CB,3) \
  W2(8,CA,CB,4)  MF5(CA,CB,4) \
  W2(6,CA,CB,5)  MF5(CA,CB,5) \
  W2(4,CA,CB,6)  MF5(CA,CB,6) \
  W2(2,CA,CB,7)  MF5(CA,CB,7) \
  W2(0,CA,CB,8)  MF5(CA,CB,8)

__global__ __launch_bounds__(256, 2) void k2_corr(
    const u16* __restrict__ Ximg2, const u16* __restrict__ Tmpl2,
    float* __restrict__ partial) {
  __shared__ float fl[5120];
  const int bid = blockIdx.x;
  const int d   = bid & 7;            // shift residue (XCD pinning heuristic)
  const int m0  = bid >> 3;           // 0..59
  const int jq  = m0 % 5;
  const int cmb = m0 / 5;             // 0..11
  const int g   = cmb & 3;
  const int uq  = cmb >> 2;           // 0..2
  const int j   = d + 8*jq;
  if (j >= 37) return;                // 36 idle pad blocks
  const int U0  = 72*uq;
  const int R0  = 10*g + U0;
  const int tid  = threadIdx.x;
  const int lane = tid & 63;
  const int w    = tid >> 6;
  const int fn16 = lane & 15;
  const int fuu  = (lane >> 4) & 1;
  const int fg   = lane >> 5;

  // SRDs (uniform bases); per-lane 32-bit voffsets; sv advance rides in soffset
  u64 pa = (u64)((const char*)Ximg2 + d*XD_STRIDE + jq*63488);
  u64 pb = (u64)((const char*)Tmpl2);
  u32x4 srdA = { (u32)pa, (u32)(pa >> 32), 0xFFFFFFFFu, 0x00020000u };
  u32x4 srdB = { (u32)pb, (u32)(pb >> 32), 0xFFFFFFFFu, 0x00020000u };
  int voffA[13], voffB[9];
#pragma unroll
  for (int q = 0; q < 13; ++q) {
    int r = R0 + fuu + 18*w + 2*q;
    if (r > 247) r = 247;             // clamped rows only ever pair with zero B
    voffA[q] = fg*63488 + fn16*16 + r*256;
  }
#pragma unroll
  for (int t = 0; t < 9; ++t)
    voffB[t] = fg*55296 + fn16*16 + (U0 + fuu + 18*w + 2*t)*256;

  f32x16 acc[5];
#pragma unroll
  for (int k = 0; k < 5; ++k)
#pragma unroll
    for (int q = 0; q < 16; ++q) acc[k][q] = 0.f;

  u32x4 A0[13], B0[9], A1[13], B1[9];
  int z0 = 0;
  // prologue: issue all 22 loads of sv=0
  ISSUE_G0(A0,B0,z0,z0)
  ISSUE_GT(A0,B0,1,z0,z0) ISSUE_GT(A0,B0,2,z0,z0) ISSUE_GT(A0,B0,3,z0,z0)
  ISSUE_GT(A0,B0,4,z0,z0) ISSUE_GT(A0,B0,5,z0,z0) ISSUE_GT(A0,B0,6,z0,z0)
  ISSUE_GT(A0,B0,7,z0,z0) ISSUE_GT(A0,B0,8,z0,z0)

#pragma unroll 1
  for (int svp = 0; svp < 6; ++svp) {
    int sA1 = (2*svp + 1)*126976, sB1 = (2*svp + 1)*110592;
    int sA2 = (2*svp + 2)*126976, sB2 = (2*svp + 2)*110592;
    HALF_PF(A0,B0, A1,B1, sA1,sB1)
    HALF_PF(A1,B1, A0,B0, sA2,sB2)
  }
  { int sA = 13*126976, sB = 13*110592;
    HALF_PF(A0,B0, A1,B1, sA,sB) }      // sv=12, prefetch sv=13
  HALF_LAST(A1,B1)                       // sv=13
  __syncthreads();

  // deterministic cross-wave fold in LDS (waves add sequentially)
  for (int z = tid; z < 5120; z += 256) fl[z] = 0.f;
  __syncthreads();
  for (int ww = 0; ww < 4; ++ww) {
    if (w == ww) {
#pragma unroll
      for (int k = 0; k < 5; ++k) {
        if (!(g == 3 && k == 4)) {    // g3 chain 4 duplicates i0=36: exclude
#pragma unroll
          for (int q = 0; q < 16; ++q)
            fl[k*1024 + q*64 + lane] += acc[k][q];
        }
      }
    }
    __syncthreads();
  }

  // emit 11 output rows [10g-1, 10g+9]; slabs [uq][g&1] are write-disjoint
  const int n = (tid >> 4) & 15;
  const int o = tid & 15;
  float* slab = partial + (uq*2 + (g & 1)) * OUT2;
  for (int ii = 0; ii < 11; ++ii) {
    const int i = 10*g - 1 + ii;
    if (i < 0 || i >= 37) continue;
    const int dd = ii - 1;
    float v;
    if (!(dd & 1)) {                  // diag: (uu,p)=(0,0)+(1,1)
      const int k = dd >> 1;
      v = F_LD(k, n, o) + F_LD(k, n+16, o+16);
    } else {
      v = 0.f;
      if (dd >= 1) v += F_LD((dd-1) >> 1, n+16, o);   // (1,0) from left chain
      const int kr = (dd+1) >> 1;
      if (kr <= 4) v += F_LD(kr, n, o+16);            // (0,1) from right chain
    }
    slab[(o*16 + n)*1369 + i*37 + j] = v;
  }
}

// ---------------- k3: reduce 6 partial slabs + scale -------------------------
__global__ void k3_reduce(const float* __restrict__ partial, float* __restrict__ out2) {
  const int idx = blockIdx.x*256 + threadIdx.x;
  float s = 0.f;
#pragma unroll
  for (int t = 0; t < 6; ++t) s += partial[t*OUT2 + idx];
  out2[idx] = s * (1.0f / 44944.0f);
}

extern "C" void kernel_launch(void* const* d_in, const int* in_sizes, int n_in,
                              void* d_out, int out_size, void* d_ws, size_t ws_size,
                              hipStream_t stream) {
  (void)in_sizes; (void)n_in; (void)out_size; (void)ws_size;
  const float* x   = (const float*)d_in[0];
  const float* ft  = (const float*)d_in[1];
  const float* fnt = (const float*)d_in[2];
  float* out = (float*)d_out;
  char*  ws  = (char*)d_ws;
  u16*   Ximg2   = (u16*)ws;
  u16*   Tmpl2   = (u16*)(ws + TMPL_OFFB);
  float* partial = (float*)(ws + PART_OFFB);
  u16*   Xc      = (u16*)(ws + XC_OFFB);

  k1_conv<<<dim3(17, 16), 256, 0, stream>>>(x, ft, fnt, out, Xc);
  k1b_expand<<<4346, 256, 0, stream>>>(Xc, (u16*)ws, partial);
  k2_corr<<<480, 256, 0, stream>>>(Ximg2, Tmpl2, partial);
  k3_reduce<<<1369, 256, 0, stream>>>(partial, out + OUT1);
}